// Round 6
// baseline (109.716 us; speedup 1.0000x reference)
//
#include <hip/hip_runtime.h>
#include <math.h>

typedef float f32x4 __attribute__((ext_vector_type(4)));

// Problem constants: bs=8, n=32, dy=64, dc=256, M=8, nm=256.
// out[b, i*8+a, j*8+c, ch] = (W[ch,:]·E[b,i,j,:] + Cpe[a*8+c, ch])
//                            * m1[b,i] * m2[b, (j%4)*8+c]
// Prologue builds Cpe = W·pe (64x256) and Wt = W^T (64x256) in d_ws.

// ---------- Prologue: Cpe[pos][ch] and Wt[d][ch] ----------
__global__ __launch_bounds__(256) void prep_kernel(const float* __restrict__ W,
                                                   float* __restrict__ Cpe,
                                                   float* __restrict__ Wt) {
    const int pos = blockIdx.x;      // 0..63 (= pe position, and = d for Wt)
    const int t   = threadIdx.x;     // channel
    Wt[pos * 256 + t] = W[t * 64 + pos];   // transpose: Wt[d][ch]
    __shared__ float peL[64];
    if (t < 64) {
        const float k2  = (float)(t & ~1);
        const float div = expf(-k2 * (logf(10000.0f) / 64.0f));
        const float arg = (float)pos * div;
        peL[t] = (t & 1) ? cosf(arg) : sinf(arg);
    }
    __syncthreads();
    const f32x4* W4 = (const f32x4*)W;
    float acc = 0.0f;
#pragma unroll
    for (int d4 = 0; d4 < 16; ++d4) {
        f32x4 w = W4[t * 16 + d4];
        acc += w.x * peL[4 * d4 + 0] + w.y * peL[4 * d4 + 1] +
               w.z * peL[4 * d4 + 2] + w.w * peL[4 * d4 + 3];
    }
    Cpe[pos * 256 + t] = acc;
}

// ---------- Main: no LDS, no barriers. Block = (b, i, qt); wave w owns
// j = qt*8 + w*2 + {0,1}; lane g owns channel quad 4g..4g+3.
// Cpe quads for a+1 are prefetched while a's stores issue (2-deep pipeline).
__global__ __launch_bounds__(256) void etoc_stream(const float* __restrict__ E,
                                                   const float* __restrict__ m1p,
                                                   const float* __restrict__ m2p,
                                                   const float* __restrict__ Wt,
                                                   const float* __restrict__ Cpe,
                                                   float* __restrict__ out) {
    const int blk = blockIdx.x;      // b*128 + i*4 + qt
    const int qt = blk & 3;
    const int i  = (blk >> 2) & 31;
    const int b  = blk >> 7;
    const int t  = threadIdx.x;
    const int w  = t >> 6;           // wave id 0..3
    const int g  = t & 63;           // channel quad
    const int j0 = qt * 8 + w * 2;   // first j of this wave (2 j's per wave)

    // ---- dot: acc[jl][4g..4g+3] = sum_d Wt[d][4g..4g+3] * E[b,i,j0+jl,d]
    const f32x4* Wt4 = (const f32x4*)Wt;
    const f32x4* E4  = (const f32x4*)E;
    const int ebase = ((b * 32 + i) * 32 + j0) * 16;   // f4 units
    f32x4 acc0 = {0,0,0,0}, acc1 = {0,0,0,0};
#pragma unroll 4
    for (int d4 = 0; d4 < 16; ++d4) {
        const f32x4 e0 = E4[ebase + d4];        // wave-uniform broadcast
        const f32x4 e1 = E4[ebase + 16 + d4];
#pragma unroll
        for (int dd = 0; dd < 4; ++dd) {
            const f32x4 wv = Wt4[(d4 * 4 + dd) * 64 + g];   // lane-coalesced
            acc0 += wv * e0[dd];
            acc1 += wv * e1[dd];
        }
    }

    // ---- masks: m(jl,c) = m1[b,i] * m2[b, ((j0+jl)%4)*8 + c]
    const float m1v = m1p[b * 32 + i];
    const float* m2b = m2p + b * 32;
    f32x4 mA[2], mB[2];
#pragma unroll
    for (int jl = 0; jl < 2; ++jl) {
        const int row = (w * 2 + jl) & 3;       // (j%4); qt*8 ≡ 0 mod 4
        mA[jl] = ((const f32x4*)(m2b + row * 8))[0] * m1v;
        mB[jl] = ((const f32x4*)(m2b + row * 8))[1] * m1v;
    }

    const f32x4* Cpe4 = (const f32x4*)Cpe;
    f32x4* out4 = (f32x4*)out;
    // out f4 index = ((b*256+i*8+a)*256 + (j0+jl)*8 + c)*64 + g
    const size_t rowb = (((size_t)(b * 256 + i * 8) * 256) + (size_t)j0 * 8) * 64 + (size_t)g;

    // ---- 2-deep pipelined store loop over a (fully unrolled, static regs)
    f32x4 q0[8], q1[8];
#pragma unroll
    for (int c = 0; c < 8; ++c) q0[c] = Cpe4[c * 64 + g];   // a = 0

#pragma unroll
    for (int a = 0; a < 8; ++a) {
        const f32x4* qc = (a & 1) ? q1 : q0;
        f32x4*       qn = (a & 1) ? q0 : q1;
        if (a < 7) {
#pragma unroll
            for (int c = 0; c < 8; ++c) qn[c] = Cpe4[((a + 1) * 8 + c) * 64 + g];
        }
#pragma unroll
        for (int jl = 0; jl < 2; ++jl) {
            const f32x4 ce = (jl == 0) ? acc0 : acc1;
            const size_t base = rowb + (size_t)(a * 256 + jl * 8) * 64;
#pragma unroll
            for (int c = 0; c < 8; ++c) {
                const float m = (c < 4) ? mA[jl][c] : mB[jl][c - 4];
                f32x4 r = (ce + qc[c]) * m;
                __builtin_nontemporal_store(r, &out4[base + (size_t)c * 64]);
            }
        }
    }
}

extern "C" void kernel_launch(void* const* d_in, const int* in_sizes, int n_in,
                              void* d_out, int out_size, void* d_ws, size_t ws_size,
                              hipStream_t stream) {
    const float* E   = (const float*)d_in[0];   // (8,32,32,64)
    const float* m1p = (const float*)d_in[1];   // (8,32,1,1)
    const float* m2p = (const float*)d_in[2];   // (8,1,32,1)
    const float* W   = (const float*)d_in[3];   // (256,64)
    float* out = (float*)d_out;                 // (8,256,256,256)

    float* Cpe = (float*)d_ws;                  // 64 KB
    float* Wt  = (float*)((char*)d_ws + 65536); // 64 KB

    prep_kernel<<<64, 256, 0, stream>>>(W, Cpe, Wt);
    etoc_stream<<<1024, 256, 0, stream>>>(E, m1p, m2p, Wt, Cpe, out);
}